// Round 13
// baseline (114.296 us; speedup 1.0000x reference)
//
#include <hip/hip_runtime.h>
#include <math.h>

#define NV 720
#define NU 736
#define NXY 512
#define WROW 3312    // window row: 92 groups x 36 dwords (8 bins + dup) = 3312 dwords
#define WPAD 3328    // LDS buffer stride (3312 + 16 so the staging tail is wave-uniform)
// Qi layout (R28, overlapped groups): element (bin u, view k) at row dword
// 4*(u + (u>>3)) + k.  Group g = u>>3 occupies dwords [36g, 36g+36): 8 bins + slot r=8
// duplicating bin 8(g+1) (written twice by the filter). Gather: e = im + (im>>3);
// bins im, im+1 = TWO ds_read_b128 at 16*e and 16*e+16 (uniform offsets incl. r=7 via
// the duplicate). Banks: 4*(g+r)+k mod 32 -> im/im+8 disjoint; residual im/im+7 alias
// is 2-way (free, m136). R26 (stride-4): 4-way conflicts, 2.74M cyc. R27 (stride-5):
// 0 conflicts but +25% staging and 5 blocks/CU. R28: both fixed (+7.8% staging, 6/CU).

// ---------------- Stage 1+2 (R28): merged-parity Ram-Lak filter --------------------------
// COMPUTE identical to R25/R26/R27 (Q values bit-identical to R18: ascending m, 4x92
// chunks ascending, center last, *DU last). Only store addressing changed (+ dup store).
__global__ __launch_bounds__(512) void filter_kernel(const float* __restrict__ sino,
                                                     float* __restrict__ Qi,
                                                     float4* __restrict__ trig,
                                                     float* __restrict__ out_zero) {
    __shared__ float s4[2][368][4];   // [parity][m][view]  11776 B
    __shared__ float wco[736];        //                     2944 B
    __shared__ float part[3][128][8]; // chunk partials     12288 B
    const int bx = blockIdx.x;
    const int q = bx & 3;             // output quadrant: r = q
    const int vb = bx >> 2;
    const int v0 = vb * 4;
    const int tid = threadIdx.x;      // [0,512)
    const int tz = tid >> 7;          // tap chunk [0,4): taps [92*tz, 92*tz+92)
    const int J0 = tid & 127;         // output slot; outputs if < 92

    // zero the atomic target (replaces the hipMemsetAsync dispatch; bp launches after)
    for (int i = bx * 512 + tid; i < NXY * NXY; i += 720 * 512)
        out_zero[i] = 0.0f;

    if (q == 0 && tid < 4) {
        int v = v0 + tid;
        float beta = (float)((double)v * (2.0 * M_PI / 720.0));
        float cb = cosf(beta), sb = sinf(beta);
        const float K = (float)(1085.6 / 1.2858);   // DSD/DU
        trig[v] = make_float4(cb * K, sb * K, cb, sb);
    }
    const float DSD2 = (float)(1085.6 * 1085.6);
    for (int i = tid; i < 4 * NU; i += 512) {   // stage 4 views, coalesced in u
        const int vv = i / NU, u = i - vv * NU;
        float us = ((float)u - 367.5f) * 1.2858f;
        float cw = 1085.6f / sqrtf(DSD2 + us * us);
        s4[u & 1][u >> 1][vv] = sino[(v0 + vv) * NU + u] * cw;
    }
    for (int i = tid; i < 736; i += 512) {
        double n = (double)(2 * i - 735);
        double a = M_PI * n * 1.2858;
        wco[i] = (float)(-1.0 / (a * a));
    }
    __syncthreads();

    const int m0 = 92 * tz;
    float a00 = 0.f, a01 = 0.f, a02 = 0.f, a03 = 0.f;   // pj=0, views 0..3
    float a10 = 0.f, a11 = 0.f, a12 = 0.f, a13 = 0.f;   // pj=1, views 0..3
    const int J0c = min(J0, 91);              // lanes J0>=92: throwaway, in-bounds
    const int y0 = J0c + 367 + 92 * q;        // weight idx y = y0 - m (pj=0), +1 (pj=1)
    const float* wp = &wco[y0 - m0];

    #pragma unroll 4
    for (int mm = 0; mm < 92; ++mm) {         // m = m0+mm ascending (R18 order)
        const int m = m0 + mm;
        const float w0 = wp[-mm];             // pj=0 }  one ds_read2_b32 (lane-varying)
        const float w1 = wp[1 - mm];          // pj=1 }
        const float4 sv1 = *(const float4*)&s4[1][m][0];   // broadcast (uniform addr)
        const float4 sv0 = *(const float4*)&s4[0][m][0];   // broadcast
        a00 = fmaf(w0, sv1.x, a00); a01 = fmaf(w0, sv1.y, a01);
        a02 = fmaf(w0, sv1.z, a02); a03 = fmaf(w0, sv1.w, a03);
        a10 = fmaf(w1, sv0.x, a10); a11 = fmaf(w1, sv0.y, a11);
        a12 = fmaf(w1, sv0.z, a12); a13 = fmaf(w1, sv0.w, a13);
    }

    if (tz != 0 && J0 < 92) {
        *(float4*)&part[tz - 1][J0][0] = make_float4(a00, a01, a02, a03);
        *(float4*)&part[tz - 1][J0][4] = make_float4(a10, a11, a12, a13);
    }
    __syncthreads();

    if (tz == 0 && J0 < 92) {
        #pragma unroll
        for (int g = 0; g < 3; ++g) {         // chunks ascending (R18 order)
            const float4 p0 = *(const float4*)&part[g][J0][0];
            const float4 p1 = *(const float4*)&part[g][J0][4];
            a00 += p0.x; a01 += p0.y; a02 += p0.z; a03 += p0.w;
            a10 += p1.x; a11 += p1.y; a12 += p1.z; a13 += p1.w;
        }
        const float H0 = (float)(1.0 / (4.0 * 1.2858 * 1.2858));
        const int mc = J0 + 92 * q;           // center tap pair index: u = j
        const float4 c0 = *(const float4*)&s4[0][mc][0];   // u = 2mc   (pj=0)
        const float4 c1 = *(const float4*)&s4[1][mc][0];   // u = 2mc+1 (pj=1)
        a00 = fmaf(H0, c0.x, a00); a01 = fmaf(H0, c0.y, a01);
        a02 = fmaf(H0, c0.z, a02); a03 = fmaf(H0, c0.w, a03);
        a10 = fmaf(H0, c1.x, a10); a11 = fmaf(H0, c1.y, a11);
        a12 = fmaf(H0, c1.z, a12); a13 = fmaf(H0, c1.w, a13);
        const float DU = 1.2858f;
        const int j0i = 2 * mc;               // even bin; j0i+1 in the same group
        const int v180 = v0 % 180;            // rows v180..v180+3 (no straddle)
        const int wq = v0 / 180;              // view slot k
        const int d0 = 4 * (j0i + (j0i >> 3)) + wq;       // bin j0i; bin j0i+1 at d0+4
        float* qr = Qi + (size_t)v180 * WROW;
        qr[0 * WROW + d0] = a00 * DU;  qr[0 * WROW + d0 + 4] = a10 * DU;
        qr[1 * WROW + d0] = a01 * DU;  qr[1 * WROW + d0 + 4] = a11 * DU;
        qr[2 * WROW + d0] = a02 * DU;  qr[2 * WROW + d0 + 4] = a12 * DU;
        qr[3 * WROW + d0] = a03 * DU;  qr[3 * WROW + d0 + 4] = a13 * DU;
        if (j0i && !(j0i & 7)) {              // duplicate: r=8 slot of previous group
            qr[0 * WROW + d0 - 4] = a00 * DU;
            qr[1 * WROW + d0 - 4] = a01 * DU;
            qr[2 * WROW + d0 - 4] = a02 * DU;
            qr[3 * WROW + d0 - 4] = a03 * DU;
        }
    }
}

// ---------------- Stage 3: bp — overlapped-group window, b128 gathers ------------------
// Staging: 3 full dwordx4 rounds + 1 wave-0-only round ([3072,3328); window padded to
// WPAD so the tail is wave-uniform — no partial-wave DMA). Tail over-reads <=16 dwords
// into the next Qi row / trig (valid memory, never gathered). Gather per geometry:
// e = im + (im>>3); TWO ds_read_b128 at winf+4e and +4e+4 replace 4 ds_read2 (half the
// DS issue, same bytes). Lessons kept: no in-loop address-dependent VMEM (R16), dbuf
// (R15), no gate reassociation (R4), setprio around gather cluster (R25).
__global__ __launch_bounds__(256) void bp_kernel(const float* __restrict__ Qi,
                                                 const float4* __restrict__ trig,
                                                 float* __restrict__ out) {
    __shared__ __align__(16) float win[2][WPAD];   // 26.6 KB double buffer -> 6 blocks/CU
    const int b = blockIdx.x;
    const int c = b & 15;                     // view chunk: base views {c, c+16, ...}
    const int blk = b >> 4;                   // 256 quadrant blocks of 16x16
    const int bx = blk >> 4;
    const int by = blk & 15;
    const int t = threadIdx.x;
    const int w = t >> 6;
    const int l = t & 63;
    const int iq = (bx << 4) + ((w >> 1) << 3) + (l >> 3);   // [0,256)
    const int jq = (by << 4) + ((w & 1) << 3) + (l & 7);     // [0,256)

    const float dx = 400.0f / 512.0f;         // 0.78125 exact
    const float X = ((float)iq - 255.5f) * dx;   // < 0
    const float Y = ((float)jq - 255.5f) * dx;   // < 0
    const float Kc = (float)(1085.6 / 1.2858);

    float acc0 = 0.0f, acc1 = 0.0f, acc2 = 0.0f, acc3 = 0.0f;
    const bool inr = fmaf(X, X, Y * Y) <= 236.5f * 236.5f;
    const bool myint = __all(inr);

    const int nk = (c < 4) ? 12 : 11;         // ceil((180-c)/16)
    const float* rowp = Qi + (size_t)c * WROW;             // window base
    const float4* tvp = trig + c;

    // preload iter 0 into buffer 0
    #pragma unroll
    for (int r = 0; r < 3; ++r)
        __builtin_amdgcn_global_load_lds(
            (const __attribute__((address_space(1))) void*)(rowp + r * 1024 + t * 4),
            (__attribute__((address_space(3))) void*)&win[0][r * 1024 + t * 4],
            16, 0, 0);
    if (w == 0)
        __builtin_amdgcn_global_load_lds(
            (const __attribute__((address_space(1))) void*)(rowp + 3072 + l * 4),
            (__attribute__((address_space(3))) void*)&win[0][3072 + l * 4],
            16, 0, 0);

    for (int it = 0; it < nk; ++it) {
        __syncthreads();                      // win[it&1] staged; prior reads of it^1 done
        if (it + 1 < nk) {
            const float* rn = rowp + 16 * WROW;
            float* wn = &win[(it + 1) & 1][0];
            #pragma unroll
            for (int r = 0; r < 3; ++r)
                __builtin_amdgcn_global_load_lds(
                    (const __attribute__((address_space(1))) void*)(rn + r * 1024 + t * 4),
                    (__attribute__((address_space(3))) void*)&wn[r * 1024 + t * 4],
                    16, 0, 0);
            if (w == 0)
                __builtin_amdgcn_global_load_lds(
                    (const __attribute__((address_space(1))) void*)(rn + 3072 + l * 4),
                    (__attribute__((address_space(3))) void*)&wn[3072 + l * 4],
                    16, 0, 0);
        }
        const float* winf = &win[it & 1][0];

        __builtin_amdgcn_s_setprio(1);        // T5: favor the gather+FMA cluster
        if (myint) {
            // ---- interior: symmetric geometry (R10-proven), b128 pair gathers --------
            const float4 tv = tvp[0];                     // cb = tv.z, sb = tv.w
            float a = fmaf(tv.z, X, tv.w * Y);            // t0
            float bb = fmaf(tv.z, Y, -tv.w * X);          // s0
            float aK = a * Kc, bK = bb * Kc;
            float D0 = 595.0f - bb, D1 = 595.0f + a, D2 = 595.0f + bb, D3 = 595.0f - a;
            float r0 = __builtin_amdgcn_rcpf(D0);
            float r1 = __builtin_amdgcn_rcpf(D1);
            float r2 = __builtin_amdgcn_rcpf(D2);
            float r3 = __builtin_amdgcn_rcpf(D3);
            float fi0 = fmaf(aK,  r0, 367.5f);
            float fi1 = fmaf(bK,  r1, 367.5f);
            float fi2 = fmaf(-aK, r2, 367.5f);
            float fi3 = fmaf(-bK, r3, 367.5f);
            int im[4] = {(int)fi0, (int)fi1, (int)fi2, (int)fi3};  // in [1,733]
            float ff[4] = {__builtin_amdgcn_fractf(fi0), __builtin_amdgcn_fractf(fi1),
                           __builtin_amdgcn_fractf(fi2), __builtin_amdgcn_fractf(fi3)};
            float gg[4] = {r0 * r0, r1 * r1, r2 * r2, r3 * r3};
            float* accp[4] = {&acc0, &acc1, &acc2, &acc3};
            #pragma unroll
            for (int m = 0; m < 4; ++m) {
                const int e = im[m] + (im[m] >> 3);       // overlapped-group index
                const float* pm = winf + 4 * e;
                const float4 qa = *(const float4*)pm;           // bin im, views 0..3
                const float4 qb = *(const float4*)(pm + 4);     // bin im+1 (dup at r=7)
                const float qa_[4] = {qa.x, qa.y, qa.z, qa.w};
                const float qb_[4] = {qb.x, qb.y, qb.z, qb.w};
                #pragma unroll
                for (int k = 0; k < 4; ++k) {
                    float val = fmaf(ff[m], qb_[k] - qa_[k], qa_[k]);
                    *accp[(m - k) & 3] = fmaf(gg[m], val, *accp[(m - k) & 3]);
                }
            }
        } else {
            // ---- exterior: R3-exact chains/gates per pixel, b128 pair gathers --------
            const float4 tvs[4] = {tvp[0], tvp[180], tvp[360], tvp[540]};
            const float pX[4] = {X, Y, -X, -Y};
            const float pY[4] = {Y, -X, -Y, X};
            float* accp[4] = {&acc0, &acc1, &acc2, &acc3};
            #pragma unroll
            for (int k = 0; k < 4; ++k) {                 // view k: one b128 pair
                const float4 tv = tvs[k];
                float fx[4], gx[4];
                int ic[4];
                #pragma unroll
                for (int j = 0; j < 4; ++j) {
                    float Xm = pX[j], Ym = pY[j];
                    float t2 = fmaf(tv.x, Xm, tv.y * Ym);               // R3-exact
                    float D  = fmaf(tv.w, Xm, fmaf(tv.z, -Ym, 595.0f)); // R3-exact
                    float rD = __builtin_amdgcn_rcpf(D);
                    float fidx = fmaf(t2, rD, 367.5f);
                    ic[j] = min(max((int)fidx, 0), NU - 2);             // v_med3_i32
                    fx[j] = __builtin_amdgcn_fractf(fidx);
                    float cen = fidx - 367.5f;                          // R3-exact gate
                    gx[j] = (__builtin_fabsf(cen) <= 367.5f) ? rD * rD : 0.0f;
                }
                #pragma unroll
                for (int j = 0; j < 4; ++j) {
                    const int e = ic[j] + (ic[j] >> 3);
                    const float* pe = winf + 4 * e;
                    float q0 = pe[k];                                   // ds_read2 {k,k+4}
                    float q1 = pe[k + 4];
                    float val = fmaf(fx[j], q1 - q0, q0);
                    *accp[j] = fmaf(gx[j], val, *accp[j]);
                }
            }
        }
        __builtin_amdgcn_s_setprio(0);
        rowp += 16 * WROW;
        tvp += 16;
    }
    const float SC = (float)(595.0 * 595.0 * 0.5 * (2.0 * M_PI / 720.0));
    const int ir = 511 - iq, jr = 511 - jq;
    unsafeAtomicAdd(&out[iq * NXY + jq], acc0 * SC);   // P0 = (iq, jq)
    unsafeAtomicAdd(&out[jq * NXY + ir], acc1 * SC);   // P1 = (jq, 511-iq)
    unsafeAtomicAdd(&out[ir * NXY + jr], acc2 * SC);   // P2 = (511-iq, 511-jq)
    unsafeAtomicAdd(&out[jr * NXY + iq], acc3 * SC);   // P3 = (511-jq, iq)
}

extern "C" void kernel_launch(void* const* d_in, const int* in_sizes, int n_in,
                              void* d_out, int out_size, void* d_ws, size_t ws_size,
                              hipStream_t stream) {
    const float* sino = (const float*)d_in[0];
    float* out = (float*)d_out;
    float* Qi = (float*)d_ws;                               // 180*3312*4 = 2,384,640 B
    float4* trig = (float4*)((char*)d_ws + (size_t)180 * WROW * sizeof(float));

    filter_kernel<<<720, 512, 0, stream>>>(sino, Qi, trig, out);   // also zeroes out
    bp_kernel<<<4096, 256, 0, stream>>>(Qi, trig, out);
}

// Round 14
// 111.647 us; speedup vs baseline: 1.0237x; 1.0237x over previous
//
#include <hip/hip_runtime.h>
#include <math.h>

#define NV 720
#define NU 736
#define NUP 768      // padded detector stride (bins 736..767 never gathered)
#define NXY 512
// Qi layout (R26, proven best of 3): Qi[v % 180][u][v / 180] -- bp window (fixed v%180,
// 4 view-slots) = 3072 floats contiguous. Measured ranking: stride-4 48.7us (2.74M
// conflict cyc) < stride-5 50.2 (0 conflicts, +25% staging) < groups 53.9 (3.83M).

// ---------------- Stage 1+2: merged-parity Ram-Lak filter (R26 verbatim) ---------------
// Q values bit-identical to R18: ascending m, 4x92 chunks ascending, center last, *DU
// last. Grid 720 = 180 vgroups x 4 r-quadrants, 512 thr: imbalance 1.07, 24 waves/CU.
__global__ __launch_bounds__(512) void filter_kernel(const float* __restrict__ sino,
                                                     float* __restrict__ Qi,
                                                     float4* __restrict__ trig,
                                                     float* __restrict__ out_zero) {
    __shared__ float s4[2][368][4];   // [parity][m][view]  11776 B
    __shared__ float wco[736];        //                     2944 B
    __shared__ float part[3][128][8]; // chunk partials     12288 B
    const int bx = blockIdx.x;
    const int q = bx & 3;             // output quadrant: r = q
    const int vb = bx >> 2;
    const int v0 = vb * 4;
    const int tid = threadIdx.x;      // [0,512)
    const int tz = tid >> 7;          // tap chunk [0,4): taps [92*tz, 92*tz+92)
    const int J0 = tid & 127;         // output slot; outputs if < 92

    // zero the atomic target (replaces the hipMemsetAsync dispatch; bp launches after)
    for (int i = bx * 512 + tid; i < NXY * NXY; i += 720 * 512)
        out_zero[i] = 0.0f;

    if (q == 0 && tid < 4) {
        int v = v0 + tid;
        float beta = (float)((double)v * (2.0 * M_PI / 720.0));
        float cb = cosf(beta), sb = sinf(beta);
        const float K = (float)(1085.6 / 1.2858);   // DSD/DU
        trig[v] = make_float4(cb * K, sb * K, cb, sb);
    }
    const float DSD2 = (float)(1085.6 * 1085.6);
    for (int i = tid; i < 4 * NU; i += 512) {   // stage 4 views, coalesced in u
        const int vv = i / NU, u = i - vv * NU;
        float us = ((float)u - 367.5f) * 1.2858f;
        float cw = 1085.6f / sqrtf(DSD2 + us * us);
        s4[u & 1][u >> 1][vv] = sino[(v0 + vv) * NU + u] * cw;
    }
    for (int i = tid; i < 736; i += 512) {
        double n = (double)(2 * i - 735);
        double a = M_PI * n * 1.2858;
        wco[i] = (float)(-1.0 / (a * a));
    }
    __syncthreads();

    const int m0 = 92 * tz;
    float a00 = 0.f, a01 = 0.f, a02 = 0.f, a03 = 0.f;   // pj=0, views 0..3
    float a10 = 0.f, a11 = 0.f, a12 = 0.f, a13 = 0.f;   // pj=1, views 0..3
    const int J0c = min(J0, 91);              // lanes J0>=92: throwaway, in-bounds
    const int y0 = J0c + 367 + 92 * q;        // weight idx y = y0 - m (pj=0), +1 (pj=1)
    const float* wp = &wco[y0 - m0];

    #pragma unroll 4
    for (int mm = 0; mm < 92; ++mm) {         // m = m0+mm ascending (R18 order)
        const int m = m0 + mm;
        const float w0 = wp[-mm];             // pj=0 }  one ds_read2_b32 (lane-varying)
        const float w1 = wp[1 - mm];          // pj=1 }
        const float4 sv1 = *(const float4*)&s4[1][m][0];   // broadcast (uniform addr)
        const float4 sv0 = *(const float4*)&s4[0][m][0];   // broadcast
        a00 = fmaf(w0, sv1.x, a00); a01 = fmaf(w0, sv1.y, a01);
        a02 = fmaf(w0, sv1.z, a02); a03 = fmaf(w0, sv1.w, a03);
        a10 = fmaf(w1, sv0.x, a10); a11 = fmaf(w1, sv0.y, a11);
        a12 = fmaf(w1, sv0.z, a12); a13 = fmaf(w1, sv0.w, a13);
    }

    if (tz != 0 && J0 < 92) {
        *(float4*)&part[tz - 1][J0][0] = make_float4(a00, a01, a02, a03);
        *(float4*)&part[tz - 1][J0][4] = make_float4(a10, a11, a12, a13);
    }
    __syncthreads();

    if (tz == 0 && J0 < 92) {
        #pragma unroll
        for (int g = 0; g < 3; ++g) {         // chunks ascending (R18 order)
            const float4 p0 = *(const float4*)&part[g][J0][0];
            const float4 p1 = *(const float4*)&part[g][J0][4];
            a00 += p0.x; a01 += p0.y; a02 += p0.z; a03 += p0.w;
            a10 += p1.x; a11 += p1.y; a12 += p1.z; a13 += p1.w;
        }
        const float H0 = (float)(1.0 / (4.0 * 1.2858 * 1.2858));
        const int mc = J0 + 92 * q;           // center tap pair index: u = j
        const float4 c0 = *(const float4*)&s4[0][mc][0];   // u = 2mc   (pj=0)
        const float4 c1 = *(const float4*)&s4[1][mc][0];   // u = 2mc+1 (pj=1)
        a00 = fmaf(H0, c0.x, a00); a01 = fmaf(H0, c0.y, a01);
        a02 = fmaf(H0, c0.z, a02); a03 = fmaf(H0, c0.w, a03);
        a10 = fmaf(H0, c1.x, a10); a11 = fmaf(H0, c1.y, a11);
        a12 = fmaf(H0, c1.z, a12); a13 = fmaf(H0, c1.w, a13);
        const int j0i = 2 * mc;
        const float DU = 1.2858f;
        // interleaved store: Qi[(v%180)][j][v/180]; v = v0+vv (all 4 share v/180)
        const int v180 = v0 % 180;            // views v180..v180+3 (no wrap: v0%4==0)
        const int wq = v0 / 180;
        float* qr = Qi + (size_t)v180 * 3072 + wq;
        qr[0 * 3072 + 4 * j0i]       = a00 * DU;  qr[0 * 3072 + 4 * (j0i + 1)] = a10 * DU;
        qr[1 * 3072 + 4 * j0i]       = a01 * DU;  qr[1 * 3072 + 4 * (j0i + 1)] = a11 * DU;
        qr[2 * 3072 + 4 * j0i]       = a02 * DU;  qr[2 * 3072 + 4 * (j0i + 1)] = a12 * DU;
        qr[3 * 3072 + 4 * j0i]       = a03 * DU;  qr[3 * 3072 + 4 * (j0i + 1)] = a13 * DU;
    }
}

// ---------------- Stage 3: bp — R26 verbatim + trig staged to LDS (R29) ----------------
// R29 theory: the in-loop global trig load (tvp[0]; exterior: 4 spread float4 loads) is
// an L2-latency VMEM dependency at the head of every gather iteration — the last
// unexplained ~10-14us of bp (neither DS nor VALU saturated). Stage all 48 float4 trig
// values into LDS once per block (guarded it<nk); in-loop trig becomes a uniform-address
// ds_read_b128 broadcast. Everything else R26-exact (best measured: 48.7us).
__global__ __launch_bounds__(256) void bp_kernel(const float* __restrict__ Qi,
                                                 const float4* __restrict__ trig,
                                                 float* __restrict__ out) {
    __shared__ float win[2][4][NUP];          // 24576 B double buffer
    __shared__ float4 tvl[12][4];             //   768 B staged trig  (25.3 KB -> 6/CU)
    const int b = blockIdx.x;
    const int c = b & 15;                     // view chunk: base views {c, c+16, ...}
    const int blk = b >> 4;                   // 256 quadrant blocks of 16x16
    const int bx = blk >> 4;
    const int by = blk & 15;
    const int t = threadIdx.x;
    const int w = t >> 6;
    const int l = t & 63;
    const int iq = (bx << 4) + ((w >> 1) << 3) + (l >> 3);   // [0,256)
    const int jq = (by << 4) + ((w & 1) << 3) + (l & 7);     // [0,256)

    const float dx = 400.0f / 512.0f;         // 0.78125 exact
    const float X = ((float)iq - 255.5f) * dx;   // < 0
    const float Y = ((float)jq - 255.5f) * dx;   // < 0
    const float Kc = (float)(1085.6 / 1.2858);

    float acc0 = 0.0f, acc1 = 0.0f, acc2 = 0.0f, acc3 = 0.0f;
    const bool inr = fmaf(X, X, Y * Y) <= 236.5f * 236.5f;
    const bool myint = __all(inr);

    const int nk = (c < 4) ? 12 : 11;         // ceil((180-c)/16)
    const float* rowp = Qi + (size_t)c * 3072;             // window base (12KB contiguous)

    // stage trig for all iterations: tvl[it][s] = trig[c + 16it + 180s]
    if (t < 48) {
        const int itx = t >> 2, s = t & 3;
        if (itx < nk) tvl[itx][s] = trig[c + 16 * itx + 180 * s];
    }

    // preload iter 0 into buffer 0 (wave w stages floats [w*768, w*768+767])
    #pragma unroll
    for (int ch = 0; ch < 3; ++ch)
        __builtin_amdgcn_global_load_lds(
            (const __attribute__((address_space(1))) void*)(rowp + w * 768 + ch * 256 + l * 4),
            (__attribute__((address_space(3))) void*)&win[0][w][ch * 256],
            16, 0, 0);

    for (int it = 0; it < nk; ++it) {
        __syncthreads();                      // win[it&1] + tvl staged; prior reads done
        if (it + 1 < nk) {
            const float* rn = rowp + 16 * 3072;
            #pragma unroll
            for (int ch = 0; ch < 3; ++ch)
                __builtin_amdgcn_global_load_lds(
                    (const __attribute__((address_space(1))) void*)(rn + w * 768 + ch * 256 + l * 4),
                    (__attribute__((address_space(3))) void*)&win[(it + 1) & 1][w][ch * 256],
                    16, 0, 0);
        }
        const float* winf = &win[it & 1][0][0];

        __builtin_amdgcn_s_setprio(1);        // T5: favor the gather+FMA cluster
        if (myint) {
            // ---- interior: symmetric geometry (R10-proven), shared-base ds_read2 -----
            const float4 tv = tvl[it][0];                 // LDS broadcast (was global)
            float a = fmaf(tv.z, X, tv.w * Y);            // t0
            float bb = fmaf(tv.z, Y, -tv.w * X);          // s0
            float aK = a * Kc, bK = bb * Kc;
            float D0 = 595.0f - bb, D1 = 595.0f + a, D2 = 595.0f + bb, D3 = 595.0f - a;
            float r0 = __builtin_amdgcn_rcpf(D0);
            float r1 = __builtin_amdgcn_rcpf(D1);
            float r2 = __builtin_amdgcn_rcpf(D2);
            float r3 = __builtin_amdgcn_rcpf(D3);
            float fi0 = fmaf(aK,  r0, 367.5f);
            float fi1 = fmaf(bK,  r1, 367.5f);
            float fi2 = fmaf(-aK, r2, 367.5f);
            float fi3 = fmaf(-bK, r3, 367.5f);
            int im[4] = {(int)fi0, (int)fi1, (int)fi2, (int)fi3};  // in [1,733]
            float ff[4] = {__builtin_amdgcn_fractf(fi0), __builtin_amdgcn_fractf(fi1),
                           __builtin_amdgcn_fractf(fi2), __builtin_amdgcn_fractf(fi3)};
            float gg[4] = {r0 * r0, r1 * r1, r2 * r2, r3 * r3};
            float* accp[4] = {&acc0, &acc1, &acc2, &acc3};
            #pragma unroll
            for (int m = 0; m < 4; ++m) {
                const float* pm = winf + 4 * im[m];       // ONE base per geometry
                #pragma unroll
                for (int k = 0; k < 4; ++k) {
                    float q0 = pm[k];                     // ds_read2 offset0:k
                    float q1 = pm[k + 4];                 //          offset1:k+4
                    float val = fmaf(ff[m], q1 - q0, q0);
                    *accp[(m - k) & 3] = fmaf(gg[m], val, *accp[(m - k) & 3]);
                }
            }
        } else {
            // ---- exterior: R3-exact chains/gates per pixel, staged ds_read2 fetch ----
            const float4 tvs[4] = {tvl[it][0], tvl[it][1], tvl[it][2], tvl[it][3]};
            const float pX[4] = {X, Y, -X, -Y};
            const float pY[4] = {Y, -X, -Y, X};
            float* accp[4] = {&acc0, &acc1, &acc2, &acc3};
            #pragma unroll
            for (int j = 0; j < 4; ++j) {
                float Xm = pX[j], Ym = pY[j];
                #pragma unroll
                for (int k = 0; k < 4; ++k) {
                    const float4 tv = tvs[k];
                    float t2 = fmaf(tv.x, Xm, tv.y * Ym);               // R3-exact
                    float D  = fmaf(tv.w, Xm, fmaf(tv.z, -Ym, 595.0f)); // R3-exact
                    float rD = __builtin_amdgcn_rcpf(D);
                    float fidx = fmaf(t2, rD, 367.5f);
                    int i0c = min(max((int)fidx, 0), NU - 2);           // v_med3_i32
                    float f = __builtin_amdgcn_fractf(fidx);
                    const float* pe = winf + 4 * i0c;
                    float q0 = pe[k];                                   // ds_read2
                    float q1 = pe[k + 4];
                    float val = fmaf(f, q1 - q0, q0);
                    float cen = fidx - 367.5f;                          // R3-exact gate
                    float g = (__builtin_fabsf(cen) <= 367.5f) ? rD * rD : 0.0f;
                    *accp[j] = fmaf(g, val, *accp[j]);
                }
            }
        }
        __builtin_amdgcn_s_setprio(0);
        rowp += 16 * 3072;
    }
    const float SC = (float)(595.0 * 595.0 * 0.5 * (2.0 * M_PI / 720.0));
    const int ir = 511 - iq, jr = 511 - jq;
    unsafeAtomicAdd(&out[iq * NXY + jq], acc0 * SC);   // P0 = (iq, jq)
    unsafeAtomicAdd(&out[jq * NXY + ir], acc1 * SC);   // P1 = (jq, 511-iq)
    unsafeAtomicAdd(&out[ir * NXY + jr], acc2 * SC);   // P2 = (511-iq, 511-jq)
    unsafeAtomicAdd(&out[jr * NXY + iq], acc3 * SC);   // P3 = (511-jq, iq)
}

extern "C" void kernel_launch(void* const* d_in, const int* in_sizes, int n_in,
                              void* d_out, int out_size, void* d_ws, size_t ws_size,
                              hipStream_t stream) {
    const float* sino = (const float*)d_in[0];
    float* out = (float*)d_out;
    float* Qi = (float*)d_ws;                               // 180*3072*4 = 2,211,840 B
    float4* trig = (float4*)((char*)d_ws + (size_t)180 * 3072 * sizeof(float));

    filter_kernel<<<720, 512, 0, stream>>>(sino, Qi, trig, out);   // also zeroes out
    bp_kernel<<<4096, 256, 0, stream>>>(Qi, trig, out);
}

// Round 15
// 110.817 us; speedup vs baseline: 1.0314x; 1.0075x over previous
//
#include <hip/hip_runtime.h>
#include <math.h>

#define NV 720
#define NU 736
#define NUP 768      // padded detector stride (bins 736..767 never gathered)
#define NXY 512
// Qi layout (R26, measured best): Qi[v % 180][u][v / 180] -- bp window (fixed v%180,
// 4 view-slots) = 3072 floats contiguous. Ranking: stride-4 48.7us < stride-5 50.2
// < trig-LDS 52.1 < groups 53.9. R29 lesson: DS pipe is binding -> R30 halves DS
// instruction count via b128 pair-gathers on the SAME layout (banks unchanged).

// ---------------- Stage 1+2: merged-parity Ram-Lak filter (R26 verbatim) ---------------
// Q values bit-identical to R18: ascending m, 4x92 chunks ascending, center last, *DU
// last. Grid 720 = 180 vgroups x 4 r-quadrants, 512 thr: imbalance 1.07, 24 waves/CU.
__global__ __launch_bounds__(512) void filter_kernel(const float* __restrict__ sino,
                                                     float* __restrict__ Qi,
                                                     float4* __restrict__ trig,
                                                     float* __restrict__ out_zero) {
    __shared__ float s4[2][368][4];   // [parity][m][view]  11776 B
    __shared__ float wco[736];        //                     2944 B
    __shared__ float part[3][128][8]; // chunk partials     12288 B
    const int bx = blockIdx.x;
    const int q = bx & 3;             // output quadrant: r = q
    const int vb = bx >> 2;
    const int v0 = vb * 4;
    const int tid = threadIdx.x;      // [0,512)
    const int tz = tid >> 7;          // tap chunk [0,4): taps [92*tz, 92*tz+92)
    const int J0 = tid & 127;         // output slot; outputs if < 92

    // zero the atomic target (replaces the hipMemsetAsync dispatch; bp launches after)
    for (int i = bx * 512 + tid; i < NXY * NXY; i += 720 * 512)
        out_zero[i] = 0.0f;

    if (q == 0 && tid < 4) {
        int v = v0 + tid;
        float beta = (float)((double)v * (2.0 * M_PI / 720.0));
        float cb = cosf(beta), sb = sinf(beta);
        const float K = (float)(1085.6 / 1.2858);   // DSD/DU
        trig[v] = make_float4(cb * K, sb * K, cb, sb);
    }
    const float DSD2 = (float)(1085.6 * 1085.6);
    for (int i = tid; i < 4 * NU; i += 512) {   // stage 4 views, coalesced in u
        const int vv = i / NU, u = i - vv * NU;
        float us = ((float)u - 367.5f) * 1.2858f;
        float cw = 1085.6f / sqrtf(DSD2 + us * us);
        s4[u & 1][u >> 1][vv] = sino[(v0 + vv) * NU + u] * cw;
    }
    for (int i = tid; i < 736; i += 512) {
        double n = (double)(2 * i - 735);
        double a = M_PI * n * 1.2858;
        wco[i] = (float)(-1.0 / (a * a));
    }
    __syncthreads();

    const int m0 = 92 * tz;
    float a00 = 0.f, a01 = 0.f, a02 = 0.f, a03 = 0.f;   // pj=0, views 0..3
    float a10 = 0.f, a11 = 0.f, a12 = 0.f, a13 = 0.f;   // pj=1, views 0..3
    const int J0c = min(J0, 91);              // lanes J0>=92: throwaway, in-bounds
    const int y0 = J0c + 367 + 92 * q;        // weight idx y = y0 - m (pj=0), +1 (pj=1)
    const float* wp = &wco[y0 - m0];

    #pragma unroll 4
    for (int mm = 0; mm < 92; ++mm) {         // m = m0+mm ascending (R18 order)
        const int m = m0 + mm;
        const float w0 = wp[-mm];             // pj=0 }  one ds_read2_b32 (lane-varying)
        const float w1 = wp[1 - mm];          // pj=1 }
        const float4 sv1 = *(const float4*)&s4[1][m][0];   // broadcast (uniform addr)
        const float4 sv0 = *(const float4*)&s4[0][m][0];   // broadcast
        a00 = fmaf(w0, sv1.x, a00); a01 = fmaf(w0, sv1.y, a01);
        a02 = fmaf(w0, sv1.z, a02); a03 = fmaf(w0, sv1.w, a03);
        a10 = fmaf(w1, sv0.x, a10); a11 = fmaf(w1, sv0.y, a11);
        a12 = fmaf(w1, sv0.z, a12); a13 = fmaf(w1, sv0.w, a13);
    }

    if (tz != 0 && J0 < 92) {
        *(float4*)&part[tz - 1][J0][0] = make_float4(a00, a01, a02, a03);
        *(float4*)&part[tz - 1][J0][4] = make_float4(a10, a11, a12, a13);
    }
    __syncthreads();

    if (tz == 0 && J0 < 92) {
        #pragma unroll
        for (int g = 0; g < 3; ++g) {         // chunks ascending (R18 order)
            const float4 p0 = *(const float4*)&part[g][J0][0];
            const float4 p1 = *(const float4*)&part[g][J0][4];
            a00 += p0.x; a01 += p0.y; a02 += p0.z; a03 += p0.w;
            a10 += p1.x; a11 += p1.y; a12 += p1.z; a13 += p1.w;
        }
        const float H0 = (float)(1.0 / (4.0 * 1.2858 * 1.2858));
        const int mc = J0 + 92 * q;           // center tap pair index: u = j
        const float4 c0 = *(const float4*)&s4[0][mc][0];   // u = 2mc   (pj=0)
        const float4 c1 = *(const float4*)&s4[1][mc][0];   // u = 2mc+1 (pj=1)
        a00 = fmaf(H0, c0.x, a00); a01 = fmaf(H0, c0.y, a01);
        a02 = fmaf(H0, c0.z, a02); a03 = fmaf(H0, c0.w, a03);
        a10 = fmaf(H0, c1.x, a10); a11 = fmaf(H0, c1.y, a11);
        a12 = fmaf(H0, c1.z, a12); a13 = fmaf(H0, c1.w, a13);
        const int j0i = 2 * mc;
        const float DU = 1.2858f;
        // interleaved store: Qi[(v%180)][j][v/180]; v = v0+vv (all 4 share v/180)
        const int v180 = v0 % 180;            // views v180..v180+3 (no wrap: v0%4==0)
        const int wq = v0 / 180;
        float* qr = Qi + (size_t)v180 * 3072 + wq;
        qr[0 * 3072 + 4 * j0i]       = a00 * DU;  qr[0 * 3072 + 4 * (j0i + 1)] = a10 * DU;
        qr[1 * 3072 + 4 * j0i]       = a01 * DU;  qr[1 * 3072 + 4 * (j0i + 1)] = a11 * DU;
        qr[2 * 3072 + 4 * j0i]       = a02 * DU;  qr[2 * 3072 + 4 * (j0i + 1)] = a12 * DU;
        qr[3 * 3072 + 4 * j0i]       = a03 * DU;  qr[3 * 3072 + 4 * (j0i + 1)] = a13 * DU;
    }
}

// ---------------- Stage 3: bp — R26 verbatim + interior b128 pair-gathers (R30) --------
// R29 lesson: DS pipe is binding (adding 4 small LDS reads/iter cost +3.4us; global trig
// is L2-hot and hidden -> restored). R30: same bytes (128B/thread/iter), HALF the DS
// instructions — bins im, im+1 x 4 views = two contiguous 16B quads at 16*im, 16*im+16
// -> 8 ds_read_b128 replace 16 ds_read2_b32 (85 vs ~64 B/cyc, m134). Bank-collision
// condition unchanged (im = im' mod 8). Exterior keeps ds_read2 {k,k+4} (per-view bins
// differ). Lessons kept: no in-loop address-dependent VMEM (R16), dbuf (R15), no gate
// reassociation (R4), setprio around gather cluster (R25).
__global__ __launch_bounds__(256) void bp_kernel(const float* __restrict__ Qi,
                                                 const float4* __restrict__ trig,
                                                 float* __restrict__ out) {
    __shared__ __align__(16) float win[2][4][NUP];   // 24 KB double buffer
    const int b = blockIdx.x;
    const int c = b & 15;                     // view chunk: base views {c, c+16, ...}
    const int blk = b >> 4;                   // 256 quadrant blocks of 16x16
    const int bx = blk >> 4;
    const int by = blk & 15;
    const int t = threadIdx.x;
    const int w = t >> 6;
    const int l = t & 63;
    const int iq = (bx << 4) + ((w >> 1) << 3) + (l >> 3);   // [0,256)
    const int jq = (by << 4) + ((w & 1) << 3) + (l & 7);     // [0,256)

    const float dx = 400.0f / 512.0f;         // 0.78125 exact
    const float X = ((float)iq - 255.5f) * dx;   // < 0
    const float Y = ((float)jq - 255.5f) * dx;   // < 0
    const float Kc = (float)(1085.6 / 1.2858);

    float acc0 = 0.0f, acc1 = 0.0f, acc2 = 0.0f, acc3 = 0.0f;
    const bool inr = fmaf(X, X, Y * Y) <= 236.5f * 236.5f;
    const bool myint = __all(inr);

    const int nk = (c < 4) ? 12 : 11;         // ceil((180-c)/16)
    const float* rowp = Qi + (size_t)c * 3072;             // window base (12KB contiguous)
    const float4* tvp = trig + c;

    // preload iter 0 into buffer 0 (wave w stages floats [w*768, w*768+767])
    #pragma unroll
    for (int ch = 0; ch < 3; ++ch)
        __builtin_amdgcn_global_load_lds(
            (const __attribute__((address_space(1))) void*)(rowp + w * 768 + ch * 256 + l * 4),
            (__attribute__((address_space(3))) void*)&win[0][w][ch * 256],
            16, 0, 0);

    for (int it = 0; it < nk; ++it) {
        __syncthreads();                      // win[it&1] staged; prior reads of it^1 done
        if (it + 1 < nk) {
            const float* rn = rowp + 16 * 3072;
            #pragma unroll
            for (int ch = 0; ch < 3; ++ch)
                __builtin_amdgcn_global_load_lds(
                    (const __attribute__((address_space(1))) void*)(rn + w * 768 + ch * 256 + l * 4),
                    (__attribute__((address_space(3))) void*)&win[(it + 1) & 1][w][ch * 256],
                    16, 0, 0);
        }
        const float* winf = &win[it & 1][0][0];

        __builtin_amdgcn_s_setprio(1);        // T5: favor the gather+FMA cluster
        if (myint) {
            // ---- interior: symmetric geometry (R10-proven), b128 pair gathers --------
            const float4 tv = tvp[0];                     // cb = tv.z, sb = tv.w
            float a = fmaf(tv.z, X, tv.w * Y);            // t0
            float bb = fmaf(tv.z, Y, -tv.w * X);          // s0
            float aK = a * Kc, bK = bb * Kc;
            float D0 = 595.0f - bb, D1 = 595.0f + a, D2 = 595.0f + bb, D3 = 595.0f - a;
            float r0 = __builtin_amdgcn_rcpf(D0);
            float r1 = __builtin_amdgcn_rcpf(D1);
            float r2 = __builtin_amdgcn_rcpf(D2);
            float r3 = __builtin_amdgcn_rcpf(D3);
            float fi0 = fmaf(aK,  r0, 367.5f);
            float fi1 = fmaf(bK,  r1, 367.5f);
            float fi2 = fmaf(-aK, r2, 367.5f);
            float fi3 = fmaf(-bK, r3, 367.5f);
            int im[4] = {(int)fi0, (int)fi1, (int)fi2, (int)fi3};  // in [1,733]
            float ff[4] = {__builtin_amdgcn_fractf(fi0), __builtin_amdgcn_fractf(fi1),
                           __builtin_amdgcn_fractf(fi2), __builtin_amdgcn_fractf(fi3)};
            float gg[4] = {r0 * r0, r1 * r1, r2 * r2, r3 * r3};
            float* accp[4] = {&acc0, &acc1, &acc2, &acc3};
            #pragma unroll
            for (int m = 0; m < 4; ++m) {
                const float* pm = winf + 4 * im[m];       // ONE base per geometry
                const float4 qa = *(const float4*)pm;           // bin im,   views 0..3
                const float4 qb = *(const float4*)(pm + 4);     // bin im+1, views 0..3
                const float qa_[4] = {qa.x, qa.y, qa.z, qa.w};
                const float qb_[4] = {qb.x, qb.y, qb.z, qb.w};
                #pragma unroll
                for (int k = 0; k < 4; ++k) {
                    float val = fmaf(ff[m], qb_[k] - qa_[k], qa_[k]);
                    *accp[(m - k) & 3] = fmaf(gg[m], val, *accp[(m - k) & 3]);
                }
            }
        } else {
            // ---- exterior: R3-exact chains/gates per pixel, staged ds_read2 fetch ----
            const float4 tvs[4] = {tvp[0], tvp[180], tvp[360], tvp[540]};
            const float pX[4] = {X, Y, -X, -Y};
            const float pY[4] = {Y, -X, -Y, X};
            float* accp[4] = {&acc0, &acc1, &acc2, &acc3};
            #pragma unroll
            for (int j = 0; j < 4; ++j) {
                float Xm = pX[j], Ym = pY[j];
                #pragma unroll
                for (int k = 0; k < 4; ++k) {
                    const float4 tv = tvs[k];
                    float t2 = fmaf(tv.x, Xm, tv.y * Ym);               // R3-exact
                    float D  = fmaf(tv.w, Xm, fmaf(tv.z, -Ym, 595.0f)); // R3-exact
                    float rD = __builtin_amdgcn_rcpf(D);
                    float fidx = fmaf(t2, rD, 367.5f);
                    int i0c = min(max((int)fidx, 0), NU - 2);           // v_med3_i32
                    float f = __builtin_amdgcn_fractf(fidx);
                    const float* pe = winf + 4 * i0c;
                    float q0 = pe[k];                                   // ds_read2 {k,k+4}
                    float q1 = pe[k + 4];
                    float val = fmaf(f, q1 - q0, q0);
                    float cen = fidx - 367.5f;                          // R3-exact gate
                    float g = (__builtin_fabsf(cen) <= 367.5f) ? rD * rD : 0.0f;
                    *accp[j] = fmaf(g, val, *accp[j]);
                }
            }
        }
        __builtin_amdgcn_s_setprio(0);
        rowp += 16 * 3072;
        tvp += 16;
    }
    const float SC = (float)(595.0 * 595.0 * 0.5 * (2.0 * M_PI / 720.0));
    const int ir = 511 - iq, jr = 511 - jq;
    unsafeAtomicAdd(&out[iq * NXY + jq], acc0 * SC);   // P0 = (iq, jq)
    unsafeAtomicAdd(&out[jq * NXY + ir], acc1 * SC);   // P1 = (jq, 511-iq)
    unsafeAtomicAdd(&out[ir * NXY + jr], acc2 * SC);   // P2 = (511-iq, 511-jq)
    unsafeAtomicAdd(&out[jr * NXY + iq], acc3 * SC);   // P3 = (511-jq, iq)
}

extern "C" void kernel_launch(void* const* d_in, const int* in_sizes, int n_in,
                              void* d_out, int out_size, void* d_ws, size_t ws_size,
                              hipStream_t stream) {
    const float* sino = (const float*)d_in[0];
    float* out = (float*)d_out;
    float* Qi = (float*)d_ws;                               // 180*3072*4 = 2,211,840 B
    float4* trig = (float4*)((char*)d_ws + (size_t)180 * 3072 * sizeof(float));

    filter_kernel<<<720, 512, 0, stream>>>(sino, Qi, trig, out);   // also zeroes out
    bp_kernel<<<4096, 256, 0, stream>>>(Qi, trig, out);
}

// Round 17
// 109.920 us; speedup vs baseline: 1.0398x; 1.0082x over previous
//
#include <hip/hip_runtime.h>
#include <math.h>

#define NV 720
#define NU 736
#define NXY 512
#define ROWD 1536    // Qh row stride in dwords (1472 used = 736 bins x 2 dwords, 64 pad)
// Qh layout (R31, fp16): half (bin u, slot s=v/180) at row half-index 4u+s, row = v%180.
// One geometry's bilinear pair (bins im,im+1 x 4 slots) = 16B at byte 8*im -> one fused
// ds_read2_b64 (offsets {0,1}). Banks {2im,2im+1} mod 32: collide only at im-span>=16
// (wave span ~13) -> ~zero interior conflicts. R30 lesson: bp DS is BYTES-bound
// (identical conflicts, halved instrs, same time) -> fp16 halves the bytes.

typedef _Float16 h2v __attribute__((ext_vector_type(2)));

// ---------------- Stage 1+2: merged-parity Ram-Lak filter (R26 compute, fp16 store) ----
// COMPUTE bit-identical to R18 in fp32 (ascending m, 4x92 chunks ascending, center last,
// *DU last); only the final store converts to fp16 (half-word stores, race-free: each
// r-quadrant block owns slot s bytes). Grid 720 = 180 vgroups x 4 r-quadrants.
__global__ __launch_bounds__(512) void filter_kernel(const float* __restrict__ sino,
                                                     float* __restrict__ Qi,
                                                     float4* __restrict__ trig,
                                                     float* __restrict__ out_zero) {
    __shared__ float s4[2][368][4];   // [parity][m][view]  11776 B
    __shared__ float wco[736];        //                     2944 B
    __shared__ float part[3][128][8]; // chunk partials     12288 B
    const int bx = blockIdx.x;
    const int q = bx & 3;             // output quadrant: r = q
    const int vb = bx >> 2;
    const int v0 = vb * 4;
    const int tid = threadIdx.x;      // [0,512)
    const int tz = tid >> 7;          // tap chunk [0,4): taps [92*tz, 92*tz+92)
    const int J0 = tid & 127;         // output slot; outputs if < 92

    // zero the atomic target (replaces the hipMemsetAsync dispatch; bp launches after)
    for (int i = bx * 512 + tid; i < NXY * NXY; i += 720 * 512)
        out_zero[i] = 0.0f;

    if (q == 0 && tid < 4) {
        int v = v0 + tid;
        float beta = (float)((double)v * (2.0 * M_PI / 720.0));
        float cb = cosf(beta), sb = sinf(beta);
        const float K = (float)(1085.6 / 1.2858);   // DSD/DU
        trig[v] = make_float4(cb * K, sb * K, cb, sb);
    }
    const float DSD2 = (float)(1085.6 * 1085.6);
    for (int i = tid; i < 4 * NU; i += 512) {   // stage 4 views, coalesced in u
        const int vv = i / NU, u = i - vv * NU;
        float us = ((float)u - 367.5f) * 1.2858f;
        float cw = 1085.6f / sqrtf(DSD2 + us * us);
        s4[u & 1][u >> 1][vv] = sino[(v0 + vv) * NU + u] * cw;
    }
    for (int i = tid; i < 736; i += 512) {
        double n = (double)(2 * i - 735);
        double a = M_PI * n * 1.2858;
        wco[i] = (float)(-1.0 / (a * a));
    }
    __syncthreads();

    const int m0 = 92 * tz;
    float a00 = 0.f, a01 = 0.f, a02 = 0.f, a03 = 0.f;   // pj=0, views 0..3
    float a10 = 0.f, a11 = 0.f, a12 = 0.f, a13 = 0.f;   // pj=1, views 0..3
    const int J0c = min(J0, 91);              // lanes J0>=92: throwaway, in-bounds
    const int y0 = J0c + 367 + 92 * q;        // weight idx y = y0 - m (pj=0), +1 (pj=1)
    const float* wp = &wco[y0 - m0];

    #pragma unroll 4
    for (int mm = 0; mm < 92; ++mm) {         // m = m0+mm ascending (R18 order)
        const int m = m0 + mm;
        const float w0 = wp[-mm];             // pj=0 }  one ds_read2_b32 (lane-varying)
        const float w1 = wp[1 - mm];          // pj=1 }
        const float4 sv1 = *(const float4*)&s4[1][m][0];   // broadcast (uniform addr)
        const float4 sv0 = *(const float4*)&s4[0][m][0];   // broadcast
        a00 = fmaf(w0, sv1.x, a00); a01 = fmaf(w0, sv1.y, a01);
        a02 = fmaf(w0, sv1.z, a02); a03 = fmaf(w0, sv1.w, a03);
        a10 = fmaf(w1, sv0.x, a10); a11 = fmaf(w1, sv0.y, a11);
        a12 = fmaf(w1, sv0.z, a12); a13 = fmaf(w1, sv0.w, a13);
    }

    if (tz != 0 && J0 < 92) {
        *(float4*)&part[tz - 1][J0][0] = make_float4(a00, a01, a02, a03);
        *(float4*)&part[tz - 1][J0][4] = make_float4(a10, a11, a12, a13);
    }
    __syncthreads();

    if (tz == 0 && J0 < 92) {
        #pragma unroll
        for (int g = 0; g < 3; ++g) {         // chunks ascending (R18 order)
            const float4 p0 = *(const float4*)&part[g][J0][0];
            const float4 p1 = *(const float4*)&part[g][J0][4];
            a00 += p0.x; a01 += p0.y; a02 += p0.z; a03 += p0.w;
            a10 += p1.x; a11 += p1.y; a12 += p1.z; a13 += p1.w;
        }
        const float H0 = (float)(1.0 / (4.0 * 1.2858 * 1.2858));
        const int mc = J0 + 92 * q;           // center tap pair index: u = j
        const float4 c0 = *(const float4*)&s4[0][mc][0];   // u = 2mc   (pj=0)
        const float4 c1 = *(const float4*)&s4[1][mc][0];   // u = 2mc+1 (pj=1)
        a00 = fmaf(H0, c0.x, a00); a01 = fmaf(H0, c0.y, a01);
        a02 = fmaf(H0, c0.z, a02); a03 = fmaf(H0, c0.w, a03);
        a10 = fmaf(H0, c1.x, a10); a11 = fmaf(H0, c1.y, a11);
        a12 = fmaf(H0, c1.z, a12); a13 = fmaf(H0, c1.w, a13);
        const int j0i = 2 * mc;
        const float DU = 1.2858f;
        // fp16 store: half (u, s) at row half-index 4u+s; rows v180..v180+3
        const int v180 = v0 % 180;            // no straddle: v0%4==0
        const int s = v0 / 180;               // slot owned by this block (byte-disjoint)
        _Float16* qh = (_Float16*)Qi;
        const int h0 = 4 * j0i + s;           // bin j0i; bin j0i+1 at h0+4
        qh[(size_t)(v180 + 0) * (ROWD * 2) + h0]     = (_Float16)(a00 * DU);
        qh[(size_t)(v180 + 0) * (ROWD * 2) + h0 + 4] = (_Float16)(a10 * DU);
        qh[(size_t)(v180 + 1) * (ROWD * 2) + h0]     = (_Float16)(a01 * DU);
        qh[(size_t)(v180 + 1) * (ROWD * 2) + h0 + 4] = (_Float16)(a11 * DU);
        qh[(size_t)(v180 + 2) * (ROWD * 2) + h0]     = (_Float16)(a02 * DU);
        qh[(size_t)(v180 + 2) * (ROWD * 2) + h0 + 4] = (_Float16)(a12 * DU);
        qh[(size_t)(v180 + 3) * (ROWD * 2) + h0]     = (_Float16)(a03 * DU);
        qh[(size_t)(v180 + 3) * (ROWD * 2) + h0 + 4] = (_Float16)(a13 * DU);
    }
}

// ---------------- Stage 3: bp — fp16 window, ds_read2_b64 gathers (R31) ----------------
// Window = 1536 dwords (6 KB) fp16; LDS dbuf 12.3 KB -> 8 blocks/CU. Staging: 1 full
// round (4 waves x 256 dwords) + 1 round on waves 0-1 (wave-uniform). Interior gather:
// ONE fused ds_read2_b64 per geometry (16B: bins im,im+1 x 4 slots fp16); lerp in packed
// fp16 (v_pk_fma_f16), 4 cvt to f32 for the acc FMA. Bytes/iter halved vs R26; interior
// conflicts ~0 (banks {2im,2im+1}, span<16). Exterior: ds_read2_b32 {0,2} + half extract.
// Lessons kept: no in-loop addr-dependent VMEM (R16), dbuf (R15), no gate reassoc (R4),
// setprio (R25), global trig is L2-hot & hidden (R29).
__global__ __launch_bounds__(256) void bp_kernel(const float* __restrict__ Qi,
                                                 const float4* __restrict__ trig,
                                                 float* __restrict__ out) {
    __shared__ __align__(16) unsigned int win[2][ROWD];   // 12,288 B double buffer
    const int b = blockIdx.x;
    const int c = b & 15;                     // view chunk: base views {c, c+16, ...}
    const int blk = b >> 4;                   // 256 quadrant blocks of 16x16
    const int bx = blk >> 4;
    const int by = blk & 15;
    const int t = threadIdx.x;
    const int w = t >> 6;
    const int l = t & 63;
    const int iq = (bx << 4) + ((w >> 1) << 3) + (l >> 3);   // [0,256)
    const int jq = (by << 4) + ((w & 1) << 3) + (l & 7);     // [0,256)

    const float dx = 400.0f / 512.0f;         // 0.78125 exact
    const float X = ((float)iq - 255.5f) * dx;   // < 0
    const float Y = ((float)jq - 255.5f) * dx;   // < 0
    const float Kc = (float)(1085.6 / 1.2858);

    float acc0 = 0.0f, acc1 = 0.0f, acc2 = 0.0f, acc3 = 0.0f;
    const bool inr = fmaf(X, X, Y * Y) <= 236.5f * 236.5f;
    const bool myint = __all(inr);

    const int nk = (c < 4) ? 12 : 11;         // ceil((180-c)/16)
    const unsigned int* rowp = (const unsigned int*)Qi + (size_t)c * ROWD;
    const float4* tvp = trig + c;

    // preload iter 0 into buffer 0: wave w -> dwords [w*256, w*256+256); waves 0,1 also
    // [1024 + w*256, ...). Wave-uniform LDS dest + per-lane src (16B/lane).
    __builtin_amdgcn_global_load_lds(
        (const __attribute__((address_space(1))) void*)(rowp + w * 256 + l * 4),
        (__attribute__((address_space(3))) void*)&win[0][w * 256], 16, 0, 0);
    if (w < 2)
        __builtin_amdgcn_global_load_lds(
            (const __attribute__((address_space(1))) void*)(rowp + 1024 + w * 256 + l * 4),
            (__attribute__((address_space(3))) void*)&win[0][1024 + w * 256], 16, 0, 0);

    for (int it = 0; it < nk; ++it) {
        __syncthreads();                      // win[it&1] staged; prior reads of it^1 done
        if (it + 1 < nk) {
            const unsigned int* rn = rowp + 16 * ROWD;
            unsigned int* wn = &win[(it + 1) & 1][0];
            __builtin_amdgcn_global_load_lds(
                (const __attribute__((address_space(1))) void*)(rn + w * 256 + l * 4),
                (__attribute__((address_space(3))) void*)&wn[w * 256], 16, 0, 0);
            if (w < 2)
                __builtin_amdgcn_global_load_lds(
                    (const __attribute__((address_space(1))) void*)(rn + 1024 + w * 256 + l * 4),
                    (__attribute__((address_space(3))) void*)&wn[1024 + w * 256], 16, 0, 0);
        }
        const unsigned int* winf = &win[it & 1][0];

        __builtin_amdgcn_s_setprio(1);        // T5: favor the gather+FMA cluster
        if (myint) {
            // ---- interior: symmetric geometry (R10-proven), ds_read2_b64 gathers -----
            const float4 tv = tvp[0];                     // cb = tv.z, sb = tv.w
            float a = fmaf(tv.z, X, tv.w * Y);            // t0
            float bb = fmaf(tv.z, Y, -tv.w * X);          // s0
            float aK = a * Kc, bK = bb * Kc;
            float D0 = 595.0f - bb, D1 = 595.0f + a, D2 = 595.0f + bb, D3 = 595.0f - a;
            float r0 = __builtin_amdgcn_rcpf(D0);
            float r1 = __builtin_amdgcn_rcpf(D1);
            float r2 = __builtin_amdgcn_rcpf(D2);
            float r3 = __builtin_amdgcn_rcpf(D3);
            float fi0 = fmaf(aK,  r0, 367.5f);
            float fi1 = fmaf(bK,  r1, 367.5f);
            float fi2 = fmaf(-aK, r2, 367.5f);
            float fi3 = fmaf(-bK, r3, 367.5f);
            int im[4] = {(int)fi0, (int)fi1, (int)fi2, (int)fi3};  // in [1,733]
            float ff[4] = {__builtin_amdgcn_fractf(fi0), __builtin_amdgcn_fractf(fi1),
                           __builtin_amdgcn_fractf(fi2), __builtin_amdgcn_fractf(fi3)};
            float gg[4] = {r0 * r0, r1 * r1, r2 * r2, r3 * r3};
            float* accp[4] = {&acc0, &acc1, &acc2, &acc3};
            #pragma unroll
            for (int m = 0; m < 4; ++m) {
                const uint2* pm = (const uint2*)(winf + 2 * im[m]);   // byte 8*im, 8B-al
                const uint2 A = pm[0];                    // bin im:   slots 01 | 23
                const uint2 B = pm[1];                    // bin im+1  (fused ds_read2_b64)
                h2v a01 = __builtin_bit_cast(h2v, A.x);
                h2v a23 = __builtin_bit_cast(h2v, A.y);
                h2v b01 = __builtin_bit_cast(h2v, B.x);
                h2v b23 = __builtin_bit_cast(h2v, B.y);
                const _Float16 fh = (_Float16)ff[m];
                const h2v fv = {fh, fh};
                const h2v v01 = (b01 - a01) * fv + a01;   // v_pk_sub + v_pk_fma
                const h2v v23 = (b23 - a23) * fv + a23;
                const float vv_[4] = {(float)v01.x, (float)v01.y,
                                      (float)v23.x, (float)v23.y};
                #pragma unroll
                for (int k = 0; k < 4; ++k)
                    *accp[(m - k) & 3] = fmaf(gg[m], vv_[k], *accp[(m - k) & 3]);
            }
        } else {
            // ---- exterior: R3-exact chains/gates per pixel, fp16 ds_read2 fetch ------
            const float4 tvs[4] = {tvp[0], tvp[180], tvp[360], tvp[540]};
            const float pX[4] = {X, Y, -X, -Y};
            const float pY[4] = {Y, -X, -Y, X};
            float* accp[4] = {&acc0, &acc1, &acc2, &acc3};
            #pragma unroll
            for (int j = 0; j < 4; ++j) {
                float Xm = pX[j], Ym = pY[j];
                #pragma unroll
                for (int k = 0; k < 4; ++k) {
                    const float4 tv = tvs[k];
                    float t2 = fmaf(tv.x, Xm, tv.y * Ym);               // R3-exact
                    float D  = fmaf(tv.w, Xm, fmaf(tv.z, -Ym, 595.0f)); // R3-exact
                    float rD = __builtin_amdgcn_rcpf(D);
                    float fidx = fmaf(t2, rD, 367.5f);
                    int i0c = min(max((int)fidx, 0), NU - 2);           // v_med3_i32
                    float f = __builtin_amdgcn_fractf(fidx);
                    const int d = 2 * i0c + (k >> 1);
                    const unsigned int w0 = winf[d];                    // ds_read2_b32
                    const unsigned int w1 = winf[d + 2];                //   offsets {0,2}
                    h2v h0 = __builtin_bit_cast(h2v, w0);
                    h2v h1 = __builtin_bit_cast(h2v, w1);
                    float q0 = (k & 1) ? (float)h0.y : (float)h0.x;     // compile-time sel
                    float q1 = (k & 1) ? (float)h1.y : (float)h1.x;
                    float val = fmaf(f, q1 - q0, q0);
                    float cen = fidx - 367.5f;                          // R3-exact gate
                    float g = (__builtin_fabsf(cen) <= 367.5f) ? rD * rD : 0.0f;
                    *accp[j] = fmaf(g, val, *accp[j]);
                }
            }
        }
        __builtin_amdgcn_s_setprio(0);
        rowp += 16 * ROWD;
        tvp += 16;
    }
    const float SC = (float)(595.0 * 595.0 * 0.5 * (2.0 * M_PI / 720.0));
    const int ir = 511 - iq, jr = 511 - jq;
    unsafeAtomicAdd(&out[iq * NXY + jq], acc0 * SC);   // P0 = (iq, jq)
    unsafeAtomicAdd(&out[jq * NXY + ir], acc1 * SC);   // P1 = (jq, 511-iq)
    unsafeAtomicAdd(&out[ir * NXY + jr], acc2 * SC);   // P2 = (511-iq, 511-jq)
    unsafeAtomicAdd(&out[jr * NXY + iq], acc3 * SC);   // P3 = (511-jq, iq)
}

extern "C" void kernel_launch(void* const* d_in, const int* in_sizes, int n_in,
                              void* d_out, int out_size, void* d_ws, size_t ws_size,
                              hipStream_t stream) {
    const float* sino = (const float*)d_in[0];
    float* out = (float*)d_out;
    float* Qi = (float*)d_ws;                               // 180*1536*4 = 1,105,920 B
    float4* trig = (float4*)((char*)d_ws + (size_t)180 * ROWD * sizeof(unsigned int));

    filter_kernel<<<720, 512, 0, stream>>>(sino, Qi, trig, out);   // also zeroes out
    bp_kernel<<<4096, 256, 0, stream>>>(Qi, trig, out);
}